// Round 14
// baseline (212.368 us; speedup 1.0000x reference)
//
#include <hip/hip_runtime.h>

typedef unsigned short u16;
typedef __attribute__((ext_vector_type(8))) _Float16 f16x8;
typedef __attribute__((ext_vector_type(4))) float f32x4;

#define MFMA_F16 __builtin_amdgcn_mfma_f32_16x16x32_f16

static __device__ __forceinline__ u16 f2h(float f) {
    return __builtin_bit_cast(u16, (_Float16)f);
}
static __device__ __forceinline__ ushort4 f4_to_h4(const float4 v) {
    ushort4 r;
    r.x = f2h(v.x); r.y = f2h(v.y); r.z = f2h(v.z); r.w = f2h(v.w);
    return r;
}

// ---------------------------------------------------------------------------
// Kernel 1: Q/K/V projection. X and W both read fp32, converted in staging
// (prep_w folded away; f4_to_h4 is RNE = bit-identical to the old prep pass).
// Epilogues via LDS transpose -> coalesced int4 stores (R13 passing).
// ---------------------------------------------------------------------------
__global__ __launch_bounds__(256) void proj_qkv(
    const float* __restrict__ X,
    const float* __restrict__ wq, const float* __restrict__ wk,
    const float* __restrict__ wv,
    const float* __restrict__ bq, const float* __restrict__ bk,
    const float* __restrict__ bv,
    u16* __restrict__ Qh, u16* __restrict__ Kh, u16* __restrict__ Vt)
{
    const int z = blockIdx.y;
    const float* __restrict__ W    = (z == 0) ? wq : (z == 1) ? wk : wv;
    const float* __restrict__ bias = (z == 0) ? bq : (z == 1) ? bk : bv;

    const int m0   = blockIdx.x * 64;          // global row (b*2048 + n0)
    const int t    = threadIdx.x;
    const int w    = t >> 6;
    const int lane = t & 63;
    const int quad = lane >> 4;
    const int l16  = lane & 15;

    __shared__ __align__(16) u16 smem[18432];  // 36864 B
    u16* Xs = smem;            // 64 x 40 during k-loop
    u16* Ws = smem + 2560;     // 256 x 40 during k-loop

    f32x4 acc[16];
#pragma unroll
    for (int i = 0; i < 16; ++i) acc[i] = f32x4{0.f, 0.f, 0.f, 0.f};

    for (int kc = 0; kc < 8; ++kc) {
        // X tile fp32 -> fp16: 512 float4-chunks, 2/thread
#pragma unroll
        for (int i = 0; i < 2; ++i) {
            const int ch = i * 256 + t;
            const int row = ch >> 3, cg = ch & 7;
            const float4 v = *(const float4*)&X[(size_t)(m0 + row) * 256 + kc * 32 + cg * 4];
            *(ushort4*)&Xs[row * 40 + cg * 4] = f4_to_h4(v);
        }
        // W tile fp32 -> fp16: 2048 float4-chunks, 8/thread
#pragma unroll
        for (int i = 0; i < 8; ++i) {
            const int ch = i * 256 + t;
            const int row = ch >> 3, cg = ch & 7;
            const float4 v = *(const float4*)&W[(size_t)row * 256 + kc * 32 + cg * 4];
            *(ushort4*)&Ws[row * 40 + cg * 4] = f4_to_h4(v);
        }
        __syncthreads();

        const f16x8 af = *(const f16x8*)&Xs[(w * 16 + l16) * 40 + quad * 8];
#pragma unroll
        for (int nt = 0; nt < 16; ++nt) {
            const f16x8 bf = *(const f16x8*)&Ws[(nt * 16 + l16) * 40 + quad * 8];
            acc[nt] = MFMA_F16(af, bf, acc[nt], 0, 0, 0);
        }
        __syncthreads();   // also makes smem safe to reuse in the epilogue
    }

    if (z < 2) {
        u16* __restrict__ Y = (z == 0) ? Qh : Kh;
#pragma unroll
        for (int nt = 0; nt < 16; ++nt) {
            const int col = nt * 16 + l16;
            const float bb = bias[col];
#pragma unroll
            for (int r = 0; r < 4; ++r)
                smem[(w * 16 + quad * 4 + r) * 264 + col] = f2h(acc[nt][r] + bb);
        }
        __syncthreads();
#pragma unroll
        for (int i = 0; i < 8; ++i) {
            const int ch = i * 256 + t;
            const int row = ch >> 5, cg = ch & 31;
            *(int4*)&Y[(size_t)(m0 + row) * 256 + cg * 8] =
                *(const int4*)&smem[row * 264 + cg * 8];
        }
    } else {
        const int b  = m0 >> 11;
        const int n0 = m0 & 2047;
#pragma unroll
        for (int nt = 0; nt < 16; ++nt) {
            const int col = nt * 16 + l16;
            const float bb = bias[col];
            ushort4 h4;
            h4.x = f2h(acc[nt][0] + bb);
            h4.y = f2h(acc[nt][1] + bb);
            h4.z = f2h(acc[nt][2] + bb);
            h4.w = f2h(acc[nt][3] + bb);
            *(ushort4*)&smem[col * 72 + w * 16 + quad * 4] = h4;
        }
        __syncthreads();
#pragma unroll
        for (int i = 0; i < 8; ++i) {
            const int ch = i * 256 + t;
            const int row = ch >> 3, cg = ch & 7;
            *(int4*)&Vt[(size_t)b * 524288 + (size_t)row * 2048 + n0 + cg * 8] =
                *(const int4*)&smem[row * 72 + cg * 8];
        }
    }
}

// ---------------------------------------------------------------------------
// Kernel 2: flash attention, transposed scores (R11-R13 passing, unchanged).
// ---------------------------------------------------------------------------
__global__ __launch_bounds__(256) void attn(
    const u16* __restrict__ Qh, const u16* __restrict__ Kg,
    const u16* __restrict__ Vt, u16* __restrict__ Op, float* __restrict__ lmp)
{
    const int nz = gridDim.z;
    const int z  = blockIdx.z;
    const int tbase = 64 / nz, trem = 64 % nz;
    const int my_tiles = tbase + (z < trem ? 1 : 0);
    const int tile0    = tbase * z + (z < trem ? z : trem);

    const int b  = blockIdx.y;
    const int q0 = blockIdx.x * 64;
    const int t    = threadIdx.x;
    const int w    = t >> 6;
    const int lane = t & 63;
    const int quad = lane >> 4;
    const int l16  = lane & 15;

    __shared__ __align__(16) u16 smem[18688];   // 37376 B
    u16* Ks = smem;                // 32 x 264
    u16* Vs = smem + 8448;         // 256 x 40
    u16* Os = smem;                // epilogue reuse: 64 x 264

    f16x8 qf[8];
    {
        const size_t qrow = (size_t)(b * 2048 + q0 + w * 16 + l16) * 256;
#pragma unroll
        for (int kc = 0; kc < 8; ++kc)
            qf[kc] = *(const f16x8*)&Qh[qrow + kc * 32 + quad * 8];
    }

    f32x4 O[16];
#pragma unroll
    for (int i = 0; i < 16; ++i) O[i] = f32x4{0.f, 0.f, 0.f, 0.f};
    float mrow = -1e30f, lrow = 0.f;

    for (int it = 0; it < my_tiles; ++it) {
        const int kt = (tile0 + it) * 32;
#pragma unroll
        for (int i = 0; i < 4; ++i) {
            const int ch = i * 256 + t;
            const int row = ch >> 5, cg = ch & 31;
            const int prow = ((row >> 2) & 3) * 8 + (row >> 4) * 4 + (row & 3);
            *(int4*)&Ks[row * 264 + cg * 8] =
                *(const int4*)&Kg[(size_t)(b * 2048 + kt + prow) * 256 + cg * 8];
        }
#pragma unroll
        for (int i = 0; i < 4; ++i) {
            const int ch = i * 256 + t;
            const int row = ch >> 2, cg = ch & 3;
            *(int4*)&Vs[row * 40 + cg * 8] =
                *(const int4*)&Vt[(size_t)b * 524288 + (size_t)row * 2048 + kt + cg * 8];
        }
        __syncthreads();

        f32x4 S[2];
        S[0] = f32x4{0.f, 0.f, 0.f, 0.f};
        S[1] = f32x4{0.f, 0.f, 0.f, 0.f};
#pragma unroll
        for (int kc = 0; kc < 8; ++kc) {
#pragma unroll
            for (int kn = 0; kn < 2; ++kn) {
                const f16x8 kf = *(const f16x8*)&Ks[(kn * 16 + l16) * 264 + kc * 32 + quad * 8];
                S[kn] = MFMA_F16(kf, qf[kc], S[kn], 0, 0, 0);
            }
        }

        float mt = fmaxf(fmaxf(fmaxf(S[0][0], S[0][1]), fmaxf(S[0][2], S[0][3])),
                         fmaxf(fmaxf(S[1][0], S[1][1]), fmaxf(S[1][2], S[1][3])));
        mt = fmaxf(mt, __shfl_xor(mt, 16));
        mt = fmaxf(mt, __shfl_xor(mt, 32));
        const float mnew = fmaxf(mrow, mt);
        const float a = __expf(mrow - mnew);
        float p[2][4];
        float s = 0.f;
#pragma unroll
        for (int kn = 0; kn < 2; ++kn)
#pragma unroll
            for (int r = 0; r < 4; ++r) {
                p[kn][r] = __expf(S[kn][r] - mnew);
                s += p[kn][r];
            }
        s += __shfl_xor(s, 16);
        s += __shfl_xor(s, 32);
        lrow = a * lrow + s;
        mrow = mnew;

        if (__any(a < 1.f)) {
#pragma unroll
            for (int dv = 0; dv < 16; ++dv)
#pragma unroll
                for (int r = 0; r < 4; ++r) O[dv][r] *= a;
        }

        f16x8 pf;
#pragma unroll
        for (int kn = 0; kn < 2; ++kn)
#pragma unroll
            for (int r = 0; r < 4; ++r)
                pf[kn * 4 + r] = (_Float16)p[kn][r];

#pragma unroll
        for (int dvt = 0; dvt < 16; ++dvt) {
            const f16x8 vf = *(const f16x8*)&Vs[(dvt * 16 + l16) * 40 + quad * 8];
            O[dvt] = MFMA_F16(vf, pf, O[dvt], 0, 0, 0);
        }
        __syncthreads();
    }

    {
        const float rl = 1.0f / lrow;
#pragma unroll
        for (int dvt = 0; dvt < 16; ++dvt) {
            ushort4 h4;
            h4.x = f2h(O[dvt][0] * rl);
            h4.y = f2h(O[dvt][1] * rl);
            h4.z = f2h(O[dvt][2] * rl);
            h4.w = f2h(O[dvt][3] * rl);
            *(ushort4*)&Os[(w * 16 + l16) * 264 + dvt * 16 + quad * 4] = h4;
        }
        if (quad == 0) {
            const int grow = b * 2048 + q0 + w * 16 + l16;
            lmp[z * 16384 + grow]        = lrow;
            lmp[(nz + z) * 16384 + grow] = mrow;
        }
    }
    __syncthreads();

    u16* __restrict__ Oz = Op + (size_t)z * 4194304;
    {
        const int row = t >> 2;
#pragma unroll
        for (int i = 0; i < 8; ++i) {
            const int chunk = (t & 3) * 8 + i;
            *(int4*)&Oz[(size_t)(b * 2048 + q0 + row) * 256 + chunk * 8] =
                *(const int4*)&Os[row * 264 + chunk * 8];
        }
    }
}

// ---------------------------------------------------------------------------
// Kernel 3: combine 2 partials + out projection + LayerNorm + LeakyReLU.
// BM=32, 256 threads, grid 512 (2 blocks/CU). Waves: w>>1 = row-half (16
// rows), w&1 = col-half (128 cols), acc[8]. LN sums cross the two col-half
// waves via LDS partials. Wo read fp32, converted in staging.
// ---------------------------------------------------------------------------
__global__ __launch_bounds__(256) void outproj_ln(
    const u16* __restrict__ Op, const float* __restrict__ lmp,
    const float* __restrict__ Wo, const float* __restrict__ bo,
    const float* __restrict__ gamma, const float* __restrict__ beta,
    float* __restrict__ out)
{
    const int m0   = blockIdx.x * 32;
    const int t    = threadIdx.x;
    const int w    = t >> 6;
    const int rh   = w >> 1;          // row-half: rows rh*16..rh*16+15
    const int chf  = w & 1;           // col-half: cols chf*128..chf*128+127
    const int lane = t & 63;
    const int quad = lane >> 4;
    const int l16  = lane & 15;

    __shared__ __align__(16) u16 Ls[32 * 40];
    __shared__ __align__(16) u16 Ws[256 * 40];
    __shared__ _Float16 w0s[32], w1s[32];
    __shared__ float psum[2][32], psum2[2][32];   // [col-half][row]

    if (t < 32) {
        const float l0 = lmp[m0 + t],          l1 = lmp[16384 + m0 + t];
        const float mm0 = lmp[32768 + m0 + t], mm1 = lmp[49152 + m0 + t];
        const float mm = fmaxf(mm0, mm1);
        const float u0 = l0 * __expf(mm0 - mm);
        const float u1 = l1 * __expf(mm1 - mm);
        const float inv = 1.0f / (u0 + u1);
        w0s[t] = (_Float16)(u0 * inv);
        w1s[t] = (_Float16)(u1 * inv);
    }
    __syncthreads();

    f32x4 acc[8];
#pragma unroll
    for (int i = 0; i < 8; ++i) acc[i] = f32x4{0.f, 0.f, 0.f, 0.f};

    for (int kc = 0; kc < 8; ++kc) {
        // combined L tile: 32 rows x 4 int4 = 128 chunks (threads 0..127)
        if (t < 128) {
            const int row = t >> 2, cg = t & 3;
            const size_t off = (size_t)(m0 + row) * 256 + kc * 32 + cg * 8;
            const f16x8 o0 = __builtin_bit_cast(f16x8, *(const int4*)&Op[off]);
            const f16x8 o1 = __builtin_bit_cast(f16x8, *(const int4*)&Op[4194304 + off]);
            const _Float16 w0 = w0s[row], w1 = w1s[row];
            f16x8 lw;
#pragma unroll
            for (int j = 0; j < 8; ++j) lw[j] = o0[j] * w0 + o1[j] * w1;
            *(int4*)&Ls[row * 40 + cg * 8] = __builtin_bit_cast(int4, lw);
        }
        // Wo tile fp32 -> fp16: 2048 float4-chunks, 8/thread
#pragma unroll
        for (int i = 0; i < 8; ++i) {
            const int ch = i * 256 + t;
            const int row = ch >> 3, cg = ch & 7;
            const float4 v = *(const float4*)&Wo[(size_t)row * 256 + kc * 32 + cg * 4];
            *(ushort4*)&Ws[row * 40 + cg * 4] = f4_to_h4(v);
        }
        __syncthreads();

        const f16x8 af = *(const f16x8*)&Ls[(rh * 16 + l16) * 40 + quad * 8];
#pragma unroll
        for (int nt = 0; nt < 8; ++nt) {
            const f16x8 bf = *(const f16x8*)&Ws[(chf * 128 + nt * 16 + l16) * 40 + quad * 8];
            acc[nt] = MFMA_F16(af, bf, acc[nt], 0, 0, 0);
        }
        __syncthreads();
    }

    // bias + per-col-half LN partial sums
    float g[8], bt[8], bb[8];
#pragma unroll
    for (int nt = 0; nt < 8; ++nt) {
        const int col = chf * 128 + nt * 16 + l16;
        bb[nt] = bo[col]; g[nt] = gamma[col]; bt[nt] = beta[col];
    }

    float h[8][4];
#pragma unroll
    for (int r = 0; r < 4; ++r) {
        float sh = 0.f, sh2 = 0.f;
#pragma unroll
        for (int nt = 0; nt < 8; ++nt) {
            h[nt][r] = acc[nt][r] + bb[nt];
            sh  += h[nt][r];
            sh2 += h[nt][r] * h[nt][r];
        }
        sh  += __shfl_xor(sh, 1);  sh  += __shfl_xor(sh, 2);
        sh  += __shfl_xor(sh, 4);  sh  += __shfl_xor(sh, 8);
        sh2 += __shfl_xor(sh2, 1); sh2 += __shfl_xor(sh2, 2);
        sh2 += __shfl_xor(sh2, 4); sh2 += __shfl_xor(sh2, 8);
        if (l16 == 0) {
            psum [chf][rh * 16 + quad * 4 + r] = sh;
            psum2[chf][rh * 16 + quad * 4 + r] = sh2;
        }
    }
    __syncthreads();

#pragma unroll
    for (int r = 0; r < 4; ++r) {
        const int row32 = rh * 16 + quad * 4 + r;
        const float sh  = psum [0][row32] + psum [1][row32];
        const float sh2 = psum2[0][row32] + psum2[1][row32];
        const float mu  = sh * (1.f / 256.f);
        const float var = fmaxf(sh2 * (1.f / 256.f) - mu * mu, 0.f);
        const float rs  = rsqrtf(var + 1e-5f);
        const size_t row = (size_t)(m0 + row32) * 256;
#pragma unroll
        for (int nt = 0; nt < 8; ++nt) {
            const float hn = (h[nt][r] - mu) * rs * g[nt] + bt[nt];
            out[row + chf * 128 + nt * 16 + l16] = (hn >= 0.f) ? hn : 0.01f * hn;
        }
    }
}

// ---------------------------------------------------------------------------
extern "C" void kernel_launch(void* const* d_in, const int* in_sizes, int n_in,
                              void* d_out, int out_size, void* d_ws, size_t ws_size,
                              hipStream_t stream)
{
    const float* x  = (const float*)d_in[0];
    const float* Wq = (const float*)d_in[1];
    const float* bq = (const float*)d_in[2];
    const float* Wk = (const float*)d_in[3];
    const float* bk = (const float*)d_in[4];
    const float* Wv = (const float*)d_in[5];
    const float* bv = (const float*)d_in[6];
    const float* Wo = (const float*)d_in[7];
    const float* bo = (const float*)d_in[8];
    const float* gm = (const float*)d_in[9];
    const float* bt = (const float*)d_in[10];
    float* out = (float*)d_out;

    // ws layout (u16): [Qh 4.19M][Kh 4.19M][Vt 4.19M][Op 2x4.19M][lmp]
    u16* Qh = (u16*)d_ws;
    u16* Kh = Qh + 4194304;
    u16* Vt = Kh + 4194304;
    u16* Op = Vt + 4194304;
    float* lmp = (float*)(Op + 2 * 4194304);  // l[2][16384], m[2][16384]

    proj_qkv   <<<dim3(256, 3),   256, 0, stream>>>(x, Wq, Wk, Wv, bq, bk, bv, Qh, Kh, Vt);
    attn       <<<dim3(32, 8, 2), 256, 0, stream>>>(Qh, Kh, Vt, Op, lmp);
    outproj_ln <<<512,            256, 0, stream>>>(Op, lmp, Wo, bo, gm, bt, out);
}